// Round 5
// baseline (1654.757 us; speedup 1.0000x reference)
//
#include <hip/hip_runtime.h>

// ---------------------------------------------------------------------------
// LongTermMemoryModule, round 5. Root cause of rounds 1-4: inputs/outputs are
// FLOAT32 per the reference (spec: "float32 -> const float*"); reading them as
// bf16 floods the pipeline with NaN-pattern bf16s (fp32 mantissa halves have
// random exponent bits). This build: device-side dtype detection, canonical
// bf16 conversion into d_ws, round-4's audited self-contained attention, and
// native-dtype (fp32 or bf16) output writes.
// ---------------------------------------------------------------------------

#define Dm  512
#define Mb  8192
#define BSr 2048
#define LP  72          // padded LDS row stride (144 B, 16B-aligned)

typedef float f32x4 __attribute__((ext_vector_type(4)));
typedef short bf16x8 __attribute__((ext_vector_type(8)));
typedef unsigned short u16x4 __attribute__((ext_vector_type(4)));

#define MFMA(a, b, c) __builtin_amdgcn_mfma_f32_16x16x32_bf16((a), (b), (c), 0, 0, 0)

__device__ __forceinline__ unsigned short f32_bf16(float f) {
  unsigned u = __builtin_bit_cast(unsigned, f);
  u += 0x7FFFu + ((u >> 16) & 1u);   // RNE
  return (unsigned short)(u >> 16);
}
__device__ __forceinline__ float bf16_f32(unsigned short h) {
  unsigned u = ((unsigned)h) << 16;
  return __builtin_bit_cast(float, u);
}

// ---------------------------------------------------------------------------
// Dtype probe: true-bf16 N(0,1) data has no u16 with exponent >= 0x90
// (|x| >= 2^17). fp32 data read as u16 has random exponent bits in every low
// half -> ~1790/8192 hits. flag = 1 means "inputs are fp32".
// ---------------------------------------------------------------------------
__global__ __launch_bounds__(256) void detect_dtype(
    const unsigned short* __restrict__ q, int* __restrict__ flag) {
  __shared__ int cnt;
  if (threadIdx.x == 0) cnt = 0;
  __syncthreads();
  int c = 0;
  for (int i = threadIdx.x; i < 8192; i += 256) {
    const unsigned e = (q[i] >> 7) & 0xFFu;
    if (e >= 0x90u) ++c;
  }
  atomicAdd(&cnt, c);
  __syncthreads();
  if (threadIdx.x == 0) *flag = (cnt > 64) ? 1 : 0;
}

// Canonicalize a tensor to bf16 (convert from fp32, or plain copy if bf16).
__global__ __launch_bounds__(256) void convert_bf16(
    const void* __restrict__ src, unsigned short* __restrict__ dst,
    const int* __restrict__ flag, int n) {
  const int i = blockIdx.x * 256 + threadIdx.x;
  if (i >= n) return;
  if (*flag)
    dst[i] = f32_bf16(((const float*)src)[i]);
  else
    dst[i] = ((const unsigned short*)src)[i];
}

// ---------------------------------------------------------------------------
// Self-contained attention (round-4 structure, canonical bf16 inputs).
// One block per (b,h); 4 waves; wave wv owns output d-stripe wv*16.
// Per 64-key tile: project K,V into LDS, QK^T (Q pre-scaled), clamped exp,
// P via shared LDS (barriered), PV. No cross-wave O reduction.
// ---------------------------------------------------------------------------
__global__ __launch_bounds__(256) void attn_self(
    const unsigned short* __restrict__ query,  // (2048,512) bf16 canonical
    const unsigned short* __restrict__ bank,   // (8192,512) bf16 canonical
    const unsigned short* __restrict__ Win,    // (1536,512) bf16 canonical
    const unsigned short* __restrict__ bin,    // (1536,)    bf16 canonical
    unsigned short* __restrict__ a_out) {      // (2048,512) bf16 staging
  __shared__ __align__(16) unsigned short QP[64 * LP];  // Q, then P tiles
  __shared__ __align__(16) unsigned short Kt[64 * LP];
  __shared__ __align__(16) unsigned short Vt[64 * LP];  // transposed: [d][key]
  __shared__ float lred[4][64];
  __shared__ float lfull[64];

  const int lane = threadIdx.x & 63;
  const int wv   = threadIdx.x >> 6;
  const int l15  = lane & 15;
  const int qd   = lane >> 4;
  const int bh   = blockIdx.x;
  const int h    = bh & 7;
  const int b    = bh >> 3;
  const int dn   = wv * 16 + l15;
  const f32x4 z4 = {0.f, 0.f, 0.f, 0.f};

  // ---- Q projection: Q[s][dn] = query[b*64+s,:] @ Wq[h*64+dn,:], pre-scaled ----
  {
    f32x4 qacc[4];
#pragma unroll
    for (int ti = 0; ti < 4; ++ti) qacc[ti] = z4;
    const unsigned short* wqp  = Win + (h * 64 + dn) * Dm + qd * 8;
    const unsigned short* qrow = query + (b * 64 + l15) * Dm + qd * 8;
#pragma unroll 4
    for (int ks = 0; ks < 16; ++ks) {
      bf16x8 wq = *(const bf16x8*)(wqp + ks * 32);
#pragma unroll
      for (int ti = 0; ti < 4; ++ti) {
        bf16x8 aq = *(const bf16x8*)(qrow + ti * 16 * Dm + ks * 32);
        qacc[ti] = MFMA(aq, wq, qacc[ti]);
      }
    }
    const float bq = bf16_f32(bin[h * 64 + dn]);
#pragma unroll
    for (int ti = 0; ti < 4; ++ti)
#pragma unroll
      for (int r = 0; r < 4; ++r)
        QP[(ti * 16 + qd * 4 + r) * LP + dn] = f32_bf16((qacc[ti][r] + bq) * 0.125f);
  }
  __syncthreads();

  bf16x8 aQ[4][2];
#pragma unroll
  for (int ti = 0; ti < 4; ++ti)
#pragma unroll
    for (int ks = 0; ks < 2; ++ks)
      aQ[ti][ks] = *(const bf16x8*)(QP + (ti * 16 + l15) * LP + ks * 32 + qd * 8);

  f32x4 oacc[4];
  float lsum[4][4];
#pragma unroll
  for (int ti = 0; ti < 4; ++ti) {
    oacc[ti] = z4;
#pragma unroll
    for (int r = 0; r < 4; ++r) lsum[ti][r] = 0.f;
  }

  const unsigned short* wkp = Win + Dm * Dm + (h * 64 + dn) * Dm + qd * 8;
  const unsigned short* wvp = Win + 2 * Dm * Dm + (h * 64 + dn) * Dm + qd * 8;
  const float bk = bf16_f32(bin[Dm + h * 64 + dn]);
  const float bv = bf16_f32(bin[2 * Dm + h * 64 + dn]);

  for (int it = 0; it < 128; ++it) {
    const int m0 = it * 64;
    __syncthreads();  // prior tile's reads drained before overwrite

    // ---- K/V projection for keys m0..m0+63, this lane's d = dn ----
    f32x4 kacc[4], vacc[4];
#pragma unroll
    for (int ti = 0; ti < 4; ++ti) { kacc[ti] = z4; vacc[ti] = z4; }
#pragma unroll 2
    for (int ks = 0; ks < 16; ++ks) {
      bf16x8 wk  = *(const bf16x8*)(wkp + ks * 32);
      bf16x8 wvv = *(const bf16x8*)(wvp + ks * 32);
#pragma unroll
      for (int ti = 0; ti < 4; ++ti) {
        bf16x8 ab = *(const bf16x8*)(bank + (m0 + ti * 16 + l15) * Dm + ks * 32 + qd * 8);
        kacc[ti] = MFMA(ab, wk, kacc[ti]);
        vacc[ti] = MFMA(ab, wvv, vacc[ti]);
      }
    }
#pragma unroll
    for (int ti = 0; ti < 4; ++ti) {
#pragma unroll
      for (int r = 0; r < 4; ++r) {
        const int key = ti * 16 + qd * 4 + r;
        Kt[key * LP + dn] = f32_bf16(kacc[ti][r] + bk);
        Vt[dn * LP + key] = f32_bf16(vacc[ti][r] + bv);
      }
    }
    __syncthreads();  // Kt/Vt visible

    // ---- QK^T for this wave's 16-key stripe (key = dn) ----
    f32x4 sfr[4];
#pragma unroll
    for (int ti = 0; ti < 4; ++ti) sfr[ti] = z4;
#pragma unroll
    for (int ks = 0; ks < 2; ++ks) {
      bf16x8 bK = *(const bf16x8*)(Kt + dn * LP + ks * 32 + qd * 8);
#pragma unroll
      for (int ti = 0; ti < 4; ++ti) sfr[ti] = MFMA(aQ[ti][ks], bK, sfr[ti]);
    }

    // ---- clamped exp (NaN-proof), lsum, write P stripe ----
#pragma unroll
    for (int ti = 0; ti < 4; ++ti) {
#pragma unroll
      for (int r = 0; r < 4; ++r) {
        float sc = fminf(fmaxf(sfr[ti][r], -30.f), 30.f);
        float e  = __expf(sc);
        lsum[ti][r] += e;
        QP[(ti * 16 + qd * 4 + r) * LP + dn] = f32_bf16(e);
      }
    }
    __syncthreads();  // P visible

    // ---- PV: O[s][dn] += P(64x64) @ V(64x64) ----
#pragma unroll
    for (int ks = 0; ks < 2; ++ks) {
      bf16x8 bV = *(const bf16x8*)(Vt + dn * LP + ks * 32 + qd * 8);
#pragma unroll
      for (int ti = 0; ti < 4; ++ti) {
        bf16x8 aP = *(const bf16x8*)(QP + (ti * 16 + l15) * LP + ks * 32 + qd * 8);
        oacc[ti] = MFMA(aP, bV, oacc[ti]);
      }
    }
  }

  // ---- l: reduce across 16 key-lanes, then across waves ----
#pragma unroll
  for (int ti = 0; ti < 4; ++ti) {
#pragma unroll
    for (int r = 0; r < 4; ++r) {
      float v = lsum[ti][r];
      v += __shfl_xor(v, 1);
      v += __shfl_xor(v, 2);
      v += __shfl_xor(v, 4);
      v += __shfl_xor(v, 8);
      if (l15 == 0) lred[wv][ti * 16 + qd * 4 + r] = v;
    }
  }
  __syncthreads();
  if (threadIdx.x < 64)
    lfull[threadIdx.x] = fmaxf(lred[0][threadIdx.x] + lred[1][threadIdx.x] +
                               lred[2][threadIdx.x] + lred[3][threadIdx.x], 1e-30f);
  __syncthreads();

  // ---- normalize + store (bf16 staging) ----
#pragma unroll
  for (int ti = 0; ti < 4; ++ti) {
#pragma unroll
    for (int r = 0; r < 4; ++r) {
      const int s = ti * 16 + qd * 4 + r;
      a_out[(b * 64 + s) * Dm + h * 64 + dn] = f32_bf16(oacc[ti][r] / lfull[s]);
    }
  }
}

// ---------------------------------------------------------------------------
// retrieved[m,n] = a_stage[m,:] @ Wout[n,:] + bout[n]; store in NATIVE dtype.
// ---------------------------------------------------------------------------
__global__ __launch_bounds__(256) void out_proj(
    const unsigned short* __restrict__ A,
    const unsigned short* __restrict__ W,
    const unsigned short* __restrict__ bias,
    const int* __restrict__ flag,
    void* __restrict__ out) {
  const int lane = threadIdx.x & 63;
  const int wv   = threadIdx.x >> 6;
  const int l15  = lane & 15;
  const int qd   = lane >> 4;
  const int mbase = blockIdx.y * 128 + wv * 32;
  const int nbase = blockIdx.x * 64;
  const int f = *flag;

  const f32x4 z4 = {0.f, 0.f, 0.f, 0.f};
  f32x4 acc[2][4];
#pragma unroll
  for (int ti = 0; ti < 2; ++ti)
#pragma unroll
    for (int j = 0; j < 4; ++j) acc[ti][j] = z4;

  const unsigned short* a0p = A + (mbase + l15) * Dm + qd * 8;
  const unsigned short* a1p = a0p + 16 * Dm;
  const unsigned short* wp  = W + (nbase + l15) * Dm + qd * 8;

#pragma unroll 4
  for (int k0 = 0; k0 < Dm; k0 += 32) {
    bf16x8 a0 = *(const bf16x8*)(a0p + k0);
    bf16x8 a1 = *(const bf16x8*)(a1p + k0);
#pragma unroll
    for (int j = 0; j < 4; ++j) {
      bf16x8 bfr = *(const bf16x8*)(wp + j * 16 * Dm + k0);
      acc[0][j] = MFMA(a0, bfr, acc[0][j]);
      acc[1][j] = MFMA(a1, bfr, acc[1][j]);
    }
  }

#pragma unroll
  for (int ti = 0; ti < 2; ++ti) {
#pragma unroll
    for (int j = 0; j < 4; ++j) {
      const int n = nbase + j * 16 + l15;
      const float bf = bf16_f32(bias[n]);
#pragma unroll
      for (int r = 0; r < 4; ++r) {
        const int m = mbase + ti * 16 + qd * 4 + r;
        const float v = acc[ti][j][r] + bf;
        if (f) ((float*)out)[m * Dm + n] = v;
        else   ((unsigned short*)out)[m * Dm + n] = f32_bf16(v);
      }
    }
  }
}

// ---------------------------------------------------------------------------
// new_bank: row r <- memory[(r-ptr) mod 8192] if offset < 2048, else bank[r].
// NATIVE dtype copy (exact): fp32 -> 16B/thread, bf16 -> 8B/thread.
// Output 1 begins at element 1048576 (byte offset depends on dtype).
// ---------------------------------------------------------------------------
__global__ __launch_bounds__(256) void bank_update(
    const void* __restrict__ memory, const void* __restrict__ bank,
    const int* __restrict__ ptrp, const int* __restrict__ flag,
    void* __restrict__ d_out) {
  const int t  = blockIdx.x * 256 + threadIdx.x;  // < 1,048,576
  const int r  = t >> 7;
  const int c4 = (t & 127) * 4;
  const int ptr = ptrp[0];
  const unsigned off = (unsigned)(r - ptr + Mb) & (Mb - 1);
  const bool fresh = off < (unsigned)BSr;
  if (*flag) {
    const float* src = fresh ? (const float*)memory + off * Dm + c4
                             : (const float*)bank   + r   * Dm + c4;
    float* dst = (float*)d_out + 1048576 + r * Dm + c4;
    *(f32x4*)dst = *(const f32x4*)src;
  } else {
    const unsigned short* src = fresh ? (const unsigned short*)memory + off * Dm + c4
                                      : (const unsigned short*)bank   + r   * Dm + c4;
    unsigned short* dst = (unsigned short*)d_out + 1048576 + r * Dm + c4;
    *(u16x4*)dst = *(const u16x4*)src;
  }
}

// ---------------------------------------------------------------------------
extern "C" void kernel_launch(void* const* d_in, const int* in_sizes, int n_in,
                              void* d_out, int out_size, void* d_ws, size_t ws_size,
                              hipStream_t stream) {
  const void* query = d_in[0];   // (32,64,512)
  const void* memry = d_in[1];   // (32,64,512)
  const void* bank  = d_in[2];   // (8192,512)
  const void* Win   = d_in[3];   // (1536,512)
  const void* bin   = d_in[4];   // (1536,)
  const void* Wout  = d_in[5];   // (512,512)
  const void* bout  = d_in[6];   // (512,)
  const int* ptrp   = (const int*)d_in[7];

  // ws layout (bytes): flag@0; canonical bf16 tensors below. Total < 16 MB.
  char* ws = (char*)d_ws;
  int*            flag    = (int*)ws;
  unsigned short* Win_c   = (unsigned short*)(ws + (1u  << 20));  //  1.0 .. 2.5 MB
  unsigned short* Wout_c  = (unsigned short*)(ws + 2621440u);     //  2.5 .. 3.0 MB
  unsigned short* q_c     = (unsigned short*)(ws + (3u  << 20));  //  3 .. 5 MB
  unsigned short* bank_c  = (unsigned short*)(ws + (5u  << 20));  //  5 .. 13 MB
  unsigned short* a_stage = (unsigned short*)(ws + (13u << 20));  // 13 .. 15 MB
  unsigned short* bin_c   = (unsigned short*)(ws + 15728640u);    // 15 MB + 3 KB
  unsigned short* bout_c  = (unsigned short*)(ws + 15794176u);    // 15.0625 MB + 1 KB

  detect_dtype<<<1, 256, 0, stream>>>((const unsigned short*)query, flag);

  convert_bf16<<<(1048576 + 255) / 256, 256, 0, stream>>>(query, q_c,   flag, 1048576);
  convert_bf16<<<(4194304 + 255) / 256, 256, 0, stream>>>(bank,  bank_c, flag, 4194304);
  convert_bf16<<<(786432  + 255) / 256, 256, 0, stream>>>(Win,   Win_c,  flag, 786432);
  convert_bf16<<<(1536    + 255) / 256, 256, 0, stream>>>(bin,   bin_c,  flag, 1536);
  convert_bf16<<<(262144  + 255) / 256, 256, 0, stream>>>(Wout,  Wout_c, flag, 262144);
  convert_bf16<<<(512     + 255) / 256, 256, 0, stream>>>(bout,  bout_c, flag, 512);

  attn_self<<<256, 256, 0, stream>>>(q_c, bank_c, Win_c, bin_c, a_stage);
  out_proj<<<dim3(8, 16), 256, 0, stream>>>(a_stage, Wout_c, bout_c, flag, d_out);
  bank_update<<<1048576 / 256, 256, 0, stream>>>(memry, bank, ptrp, flag, d_out);
}

// Round 6
// 250.719 us; speedup vs baseline: 6.6001x; 6.6001x over previous
//
#include <hip/hip_runtime.h>

// ---------------------------------------------------------------------------
// LongTermMemoryModule, round 6. Inputs/outputs are FP32 (confirmed round 5).
// Pipeline: fp32->bf16 convert -> q/k/v NT-GEMM projections (K/V computed ONCE,
// staged in d_out's bank region) -> split-M attention (1024 blocks, barrier-
// free main loop, per-wave P roundtrip) -> combine -> out proj (fp32 out) ->
// bank scatter (fp32, overwrites K/V scratch).
// Shapes: B=32 S=64 D=512 M=8192 H=8 hd=64.
// ---------------------------------------------------------------------------

#define Dm  512
#define Mb  8192
#define BSr 2048
#define PLP 36          // P tile LDS row stride (u16): conflict-free b128 reads

typedef float f32x4 __attribute__((ext_vector_type(4)));
typedef short bf16x8 __attribute__((ext_vector_type(8)));
typedef unsigned short u16x4 __attribute__((ext_vector_type(4)));

#define MFMA(a, b, c) __builtin_amdgcn_mfma_f32_16x16x32_bf16((a), (b), (c), 0, 0, 0)

__device__ __forceinline__ unsigned short f32_bf16(float f) {
  unsigned u = __builtin_bit_cast(unsigned, f);
  u += 0x7FFFu + ((u >> 16) & 1u);   // RNE
  return (unsigned short)(u >> 16);
}
__device__ __forceinline__ unsigned short f32_bf16_trunc(float f) {
  return (unsigned short)(__builtin_bit_cast(unsigned, f) >> 16);
}
__device__ __forceinline__ float bf16_f32(unsigned short h) {
  unsigned u = ((unsigned)h) << 16;
  return __builtin_bit_cast(float, u);
}

// ---------------------------------------------------------------------------
// Merged fp32 -> bf16 canonicalization of all 6 tensors. 4 elems/thread.
// Element space: q[0,1048576) bank[..,5242880) Win[..,6029312) bin[..,6030848)
// Wout[..,6292992) bout[..,6293504).  Grid 6146 x 256 covers exactly.
// ---------------------------------------------------------------------------
__global__ __launch_bounds__(256) void convert_all(
    const float* __restrict__ q, const float* __restrict__ bank,
    const float* __restrict__ Win, const float* __restrict__ bin,
    const float* __restrict__ Wout, const float* __restrict__ bout,
    unsigned short* __restrict__ q_c, unsigned short* __restrict__ bank_c,
    unsigned short* __restrict__ Win_c, unsigned short* __restrict__ bin_c,
    unsigned short* __restrict__ Wout_c, unsigned short* __restrict__ bout_c) {
  const int e = (blockIdx.x * 256 + threadIdx.x) * 4;
  const float* src; unsigned short* dst; int off;
  if (e < 1048576)      { src = q;    dst = q_c;    off = e; }
  else if (e < 5242880) { src = bank; dst = bank_c; off = e - 1048576; }
  else if (e < 6029312) { src = Win;  dst = Win_c;  off = e - 5242880; }
  else if (e < 6030848) { src = bin;  dst = bin_c;  off = e - 6029312; }
  else if (e < 6292992) { src = Wout; dst = Wout_c; off = e - 6030848; }
  else                  { src = bout; dst = bout_c; off = e - 6292992; }
  f32x4 v = *(const f32x4*)(src + off);
  u16x4 o;
#pragma unroll
  for (int j = 0; j < 4; ++j) o[j] = f32_bf16(v[j]);
  *(u16x4*)(dst + off) = o;
}

// ---------------------------------------------------------------------------
// C[m,n] = (sum_k A[m,k] * W[n,k] + bias[n]) * oscale   (NT GEMM, K=512)
// Per wave 32(m) x 64(n); block = 4 waves -> 128 x 64. grid (512/64, rows/128).
// MODE output permutation:
//   0: q scratch [bh][s][d]   1: k scratch [h][m][d]   2: vT scratch [h][d][m]
// ---------------------------------------------------------------------------
template <int MODE>
__global__ __launch_bounds__(256) void proj_gemm(
    const unsigned short* __restrict__ A,
    const unsigned short* __restrict__ W,
    const unsigned short* __restrict__ bias,
    unsigned short* __restrict__ out, float oscale) {
  const int lane = threadIdx.x & 63;
  const int wv   = threadIdx.x >> 6;
  const int l15  = lane & 15;
  const int qd   = lane >> 4;
  const int mbase = blockIdx.y * 128 + wv * 32;
  const int nbase = blockIdx.x * 64;

  const f32x4 z4 = {0.f, 0.f, 0.f, 0.f};
  f32x4 acc[2][4];
#pragma unroll
  for (int ti = 0; ti < 2; ++ti)
#pragma unroll
    for (int j = 0; j < 4; ++j) acc[ti][j] = z4;

  const unsigned short* a0p = A + (mbase + l15) * Dm + qd * 8;
  const unsigned short* a1p = a0p + 16 * Dm;
  const unsigned short* wp  = W + (nbase + l15) * Dm + qd * 8;

#pragma unroll 4
  for (int k0 = 0; k0 < Dm; k0 += 32) {
    bf16x8 a0 = *(const bf16x8*)(a0p + k0);
    bf16x8 a1 = *(const bf16x8*)(a1p + k0);
#pragma unroll
    for (int j = 0; j < 4; ++j) {
      bf16x8 b = *(const bf16x8*)(wp + j * 16 * Dm + k0);
      acc[0][j] = MFMA(a0, b, acc[0][j]);
      acc[1][j] = MFMA(a1, b, acc[1][j]);
    }
  }

#pragma unroll
  for (int ti = 0; ti < 2; ++ti) {
#pragma unroll
    for (int j = 0; j < 4; ++j) {
      const int n = nbase + j * 16 + l15;
      const float bf = bf16_f32(bias[n]);
#pragma unroll
      for (int r = 0; r < 4; ++r) {
        const int m = mbase + ti * 16 + qd * 4 + r;
        const float v = (acc[ti][j][r] + bf) * oscale;
        unsigned idx;
        if (MODE == 0)
          idx = ((unsigned)(m >> 6) * 8u + (unsigned)(n >> 6)) * 4096u +
                (unsigned)(m & 63) * 64u + (unsigned)(n & 63);
        else if (MODE == 1)
          idx = (unsigned)(n >> 6) * 524288u + (unsigned)m * 64u + (unsigned)(n & 63);
        else
          idx = (unsigned)n * 8192u + (unsigned)m;
        out[idx] = f32_bf16(v);
      }
    }
  }
}

// ---------------------------------------------------------------------------
// Split-M attention partial: block = (bh, part); 4 waves each own interleaved
// 32-key tiles of this part's 2048 keys. Barrier-free main loop: P transform
// through per-wave-private LDS tile, ordered by two lgkmcnt fences (RAW after
// writes, WAR at loop top). Epilogue: cross-wave O/l reduction through LDS
// (red[] aliases Plds), O_part stored bf16.
// ---------------------------------------------------------------------------
__global__ __launch_bounds__(256) void attn_partial(
    const unsigned short* __restrict__ q_s,   // [bh][s][d], pre-scaled by 1/8
    const unsigned short* __restrict__ k_s,   // [h][m][d]
    const unsigned short* __restrict__ vT_s,  // [h][d][m]
    unsigned short* __restrict__ O_part,      // [bh][part][s][d] bf16
    float* __restrict__ l_part) {             // [bh][part][s]
  __shared__ __align__(16) unsigned short Plds[4][64 * PLP];  // 36 KB
  __shared__ float lred[4][64];
  float* red = (float*)&Plds[0][0];  // epilogue alias: [wv*1024 + idx]

  const int lane = threadIdx.x & 63;
  const int wv   = threadIdx.x >> 6;
  const int l15  = lane & 15;
  const int qd   = lane >> 4;
  const int bh   = blockIdx.x >> 2;
  const int part = blockIdx.x & 3;
  const int h    = bh & 7;

  const unsigned short* qp = q_s + bh * 4096;
  const unsigned short* kp = k_s + h * (Mb * 64);
  const unsigned short* vp = vT_s + h * (Mb * 64);

  // Q A-fragments: A[s = ti*16 + l15][k = ks*32 + qd*8 + j]
  bf16x8 aQ[4][2];
#pragma unroll
  for (int ti = 0; ti < 4; ++ti)
#pragma unroll
    for (int ks = 0; ks < 2; ++ks)
      aQ[ti][ks] = *(const bf16x8*)(qp + (ti * 16 + l15) * 64 + ks * 32 + qd * 8);

  const f32x4 z4 = {0.f, 0.f, 0.f, 0.f};
  f32x4 oacc[4][4];
  float lsum[4][4];
#pragma unroll
  for (int ti = 0; ti < 4; ++ti)
#pragma unroll
    for (int j = 0; j < 4; ++j) { oacc[ti][j] = z4; lsum[ti][j] = 0.f; }

  unsigned short* myP = Plds[wv];

  for (int it = 0; it < 16; ++it) {
    const int m0 = part * 2048 + (it * 4 + wv) * 32;

    // WAR fence: previous iteration's P reads ordered before this one's writes
    __asm__ volatile("s_waitcnt lgkmcnt(0)" ::: "memory");

    // --- QK^T: 64(s) x 32(keys), fp32 ---
    f32x4 sfr[4][2];
#pragma unroll
    for (int ti = 0; ti < 4; ++ti)
#pragma unroll
      for (int tj = 0; tj < 2; ++tj) sfr[ti][tj] = z4;
#pragma unroll
    for (int tj = 0; tj < 2; ++tj) {
#pragma unroll
      for (int ks = 0; ks < 2; ++ks) {
        bf16x8 bK = *(const bf16x8*)(kp + (m0 + tj * 16 + l15) * 64 + ks * 32 + qd * 8);
#pragma unroll
        for (int ti = 0; ti < 4; ++ti) sfr[ti][tj] = MFMA(aQ[ti][ks], bK, sfr[ti][tj]);
      }
    }

    // --- exp, accumulate l, write P (C-layout -> rowmajor, trunc to bf16) ---
#pragma unroll
    for (int ti = 0; ti < 4; ++ti) {
#pragma unroll
      for (int tj = 0; tj < 2; ++tj) {
#pragma unroll
        for (int r = 0; r < 4; ++r) {
          float e = __expf(sfr[ti][tj][r]);     // scores pre-scaled; |s| <~ 8
          lsum[ti][r] += e;
          myP[(ti * 16 + qd * 4 + r) * PLP + tj * 16 + l15] = f32_bf16_trunc(e);
        }
      }
    }

    // RAW fence: drain P writes before vector re-reads (same-wave DS in-order)
    __asm__ volatile("s_waitcnt lgkmcnt(0)" ::: "memory");

    // --- read P in A-operand layout ---
    bf16x8 aP[4];
#pragma unroll
    for (int ti = 0; ti < 4; ++ti)
      aP[ti] = *(const bf16x8*)(myP + (ti * 16 + l15) * PLP + qd * 8);

    // --- PV: O += P(64x32) @ V(32x64); B[k][n] = vT[d = dt*16+l15][m0+qd*8+j] ---
#pragma unroll
    for (int dt = 0; dt < 4; ++dt) {
      bf16x8 bV = *(const bf16x8*)(vp + (dt * 16 + l15) * Mb + m0 + qd * 8);
#pragma unroll
      for (int ti = 0; ti < 4; ++ti) oacc[ti][dt] = MFMA(aP[ti], bV, oacc[ti][dt]);
    }
  }

  // --- l: reduce across 16 key-lanes, then across waves ---
#pragma unroll
  for (int ti = 0; ti < 4; ++ti) {
#pragma unroll
    for (int r = 0; r < 4; ++r) {
      float v = lsum[ti][r];
      v += __shfl_xor(v, 1);
      v += __shfl_xor(v, 2);
      v += __shfl_xor(v, 4);
      v += __shfl_xor(v, 8);
      if (l15 == 0) lred[wv][ti * 16 + qd * 4 + r] = v;
    }
  }
  __syncthreads();
  if (threadIdx.x < 64)
    l_part[(bh * 4 + part) * 64 + threadIdx.x] =
        lred[0][threadIdx.x] + lred[1][threadIdx.x] +
        lred[2][threadIdx.x] + lred[3][threadIdx.x];

  // --- O: reduce across waves in 4 chunks (red aliases Plds), store bf16 ---
  unsigned short* Ob = O_part + (bh * 4 + part) * 4096;
  for (int ti = 0; ti < 4; ++ti) {
    __syncthreads();
#pragma unroll
    for (int dt = 0; dt < 4; ++dt)
#pragma unroll
      for (int r = 0; r < 4; ++r)
        red[wv * 1024 + dt * 256 + r * 64 + lane] = oacc[ti][dt][r];
    __syncthreads();
#pragma unroll
    for (int j = 0; j < 4; ++j) {
      const int idx = j * 256 + threadIdx.x;
      const float s = red[idx] + red[1024 + idx] + red[2048 + idx] + red[3072 + idx];
      const int ln = idx & 63;
      const int r  = (idx >> 6) & 3;
      const int dt = idx >> 8;
      const int srow = ti * 16 + (ln >> 4) * 4 + r;
      const int dcol = dt * 16 + (ln & 15);
      Ob[srow * 64 + dcol] = f32_bf16(s);
    }
  }
}

// ---------------------------------------------------------------------------
// Combine partials, normalize, permute to (b*64+s, h*64+d) bf16 for out-proj.
// ---------------------------------------------------------------------------
__global__ __launch_bounds__(256) void attn_combine(
    const unsigned short* __restrict__ O_part, const float* __restrict__ l_part,
    unsigned short* __restrict__ a_stage) {
  const int e  = (blockIdx.x * 256 + threadIdx.x) * 4;  // < 1048576
  const int bh = e >> 12;
  const int rem = e & 4095;
  const int s  = rem >> 6;
  const int d  = rem & 63;
  float acc[4] = {0.f, 0.f, 0.f, 0.f};
  float l = 0.f;
#pragma unroll
  for (int p = 0; p < 4; ++p) {
    u16x4 v = *(const u16x4*)(O_part + (bh * 4 + p) * 4096 + rem);
#pragma unroll
    for (int j = 0; j < 4; ++j) acc[j] += bf16_f32(v[j]);
    l += l_part[(bh * 4 + p) * 64 + s];
  }
  const int b = bh >> 3, h = bh & 7;
  u16x4 o;
#pragma unroll
  for (int j = 0; j < 4; ++j) o[j] = f32_bf16(acc[j] / l);
  *(u16x4*)(a_stage + (b * 64 + s) * 512 + h * 64 + d) = o;
}

// ---------------------------------------------------------------------------
// retrieved[m,n] = a_stage[m,:] @ Wout[n,:] + bout[n]  -> fp32 d_out.
// ---------------------------------------------------------------------------
__global__ __launch_bounds__(256) void out_proj(
    const unsigned short* __restrict__ A,
    const unsigned short* __restrict__ W,
    const unsigned short* __restrict__ bias,
    float* __restrict__ out) {
  const int lane = threadIdx.x & 63;
  const int wv   = threadIdx.x >> 6;
  const int l15  = lane & 15;
  const int qd   = lane >> 4;
  const int mbase = blockIdx.y * 128 + wv * 32;
  const int nbase = blockIdx.x * 64;

  const f32x4 z4 = {0.f, 0.f, 0.f, 0.f};
  f32x4 acc[2][4];
#pragma unroll
  for (int ti = 0; ti < 2; ++ti)
#pragma unroll
    for (int j = 0; j < 4; ++j) acc[ti][j] = z4;

  const unsigned short* a0p = A + (mbase + l15) * Dm + qd * 8;
  const unsigned short* a1p = a0p + 16 * Dm;
  const unsigned short* wp  = W + (nbase + l15) * Dm + qd * 8;

#pragma unroll 4
  for (int k0 = 0; k0 < Dm; k0 += 32) {
    bf16x8 a0 = *(const bf16x8*)(a0p + k0);
    bf16x8 a1 = *(const bf16x8*)(a1p + k0);
#pragma unroll
    for (int j = 0; j < 4; ++j) {
      bf16x8 bfr = *(const bf16x8*)(wp + j * 16 * Dm + k0);
      acc[0][j] = MFMA(a0, bfr, acc[0][j]);
      acc[1][j] = MFMA(a1, bfr, acc[1][j]);
    }
  }

#pragma unroll
  for (int ti = 0; ti < 2; ++ti) {
#pragma unroll
    for (int j = 0; j < 4; ++j) {
      const int n = nbase + j * 16 + l15;
      const float bf = bf16_f32(bias[n]);
#pragma unroll
      for (int r = 0; r < 4; ++r) {
        const int m = mbase + ti * 16 + qd * 4 + r;
        out[m * Dm + n] = acc[ti][j][r] + bf;
      }
    }
  }
}

// ---------------------------------------------------------------------------
// new_bank (fp32): row r <- memory[(r-ptr) mod 8192] if offset < 2048 else
// bank[r]. 16 B/thread. Overwrites the K/V scratch staged in this region.
// ---------------------------------------------------------------------------
__global__ __launch_bounds__(256) void bank_update(
    const float* __restrict__ memory, const float* __restrict__ bank,
    const int* __restrict__ ptrp, float* __restrict__ out_bank) {
  const int t  = blockIdx.x * 256 + threadIdx.x;  // < 1,048,576
  const int r  = t >> 7;
  const int c4 = (t & 127) * 4;
  const int ptr = ptrp[0];
  const unsigned off = (unsigned)(r - ptr + Mb) & (Mb - 1);
  const float* src = (off < (unsigned)BSr) ? memory + off * Dm + c4
                                           : bank + r * Dm + c4;
  *(f32x4*)(out_bank + r * Dm + c4) = *(const f32x4*)src;
}

// ---------------------------------------------------------------------------
extern "C" void kernel_launch(void* const* d_in, const int* in_sizes, int n_in,
                              void* d_out, int out_size, void* d_ws, size_t ws_size,
                              hipStream_t stream) {
  const float* query = (const float*)d_in[0];
  const float* memry = (const float*)d_in[1];
  const float* bank  = (const float*)d_in[2];
  const float* Win   = (const float*)d_in[3];
  const float* bin   = (const float*)d_in[4];
  const float* Wout  = (const float*)d_in[5];
  const float* bout  = (const float*)d_in[6];
  const int*   ptrp  = (const int*)d_in[7];
  float* outf = (float*)d_out;

  // ws layout (14.3 MB; round 5 proved >= 15.8 MB exists). Aliases are
  // lifetime-disjoint: a_stage reuses q_c; O_part reuses bank_c.
  char* ws = (char*)d_ws;
  unsigned short* q_c     = (unsigned short*)(ws);                 //  0 ..  2 MB
  unsigned short* a_stage = (unsigned short*)(ws);                 //  (alias)
  unsigned short* bank_c  = (unsigned short*)(ws + (2u << 20));    //  2 .. 10 MB
  unsigned short* O_part  = (unsigned short*)(ws + (2u << 20));    //  (alias)
  unsigned short* Win_c   = (unsigned short*)(ws + (10u << 20));   // 10 .. 11.5 MB
  unsigned short* Wout_c  = (unsigned short*)(ws + 12058624u);     // 11.5 .. 12 MB
  unsigned short* q_s     = (unsigned short*)(ws + (12u << 20));   // 12 .. 14 MB
  float*          l_part  = (float*)(ws + (14u << 20));            // 14 .. 14.25 MB
  unsigned short* bin_c   = (unsigned short*)(ws + 14942208u);     // + 3 KB
  unsigned short* bout_c  = (unsigned short*)(ws + 14945280u);     // + 1 KB

  // K/V scratch lives in d_out's 16 MB bank region; bank_update rewrites it.
  unsigned short* kv = (unsigned short*)(outf + 1048576);
  unsigned short* k_s  = kv;             // 8 MB: [h][m][d]
  unsigned short* vT_s = kv + 4194304;   // 8 MB: [h][d][m]

  convert_all<<<6146, 256, 0, stream>>>(query, bank, Win, bin, Wout, bout,
                                        q_c, bank_c, Win_c, bin_c, Wout_c, bout_c);

  proj_gemm<0><<<dim3(8, 16), 256, 0, stream>>>(q_c, Win_c, bin_c, q_s, 0.125f);
  proj_gemm<1><<<dim3(8, 64), 256, 0, stream>>>(bank_c, Win_c + 512 * 512,
                                                bin_c + 512, k_s, 1.0f);
  proj_gemm<2><<<dim3(8, 64), 256, 0, stream>>>(bank_c, Win_c + 2 * 512 * 512,
                                                bin_c + 1024, vT_s, 1.0f);

  attn_partial<<<1024, 256, 0, stream>>>(q_s, k_s, vT_s, O_part, l_part);
  attn_combine<<<1024, 256, 0, stream>>>(O_part, l_part, a_stage);

  out_proj<<<dim3(8, 16), 256, 0, stream>>>(a_stage, Wout_c, bout_c, outf);
  bank_update<<<4096, 256, 0, stream>>>(memry, bank, ptrp, outf + 1048576);
}

// Round 7
// 241.802 us; speedup vs baseline: 6.8434x; 1.0369x over previous
//
#include <hip/hip_runtime.h>

// ---------------------------------------------------------------------------
// LongTermMemoryModule, round 7. FP32 in/out (confirmed). Changes vs r6:
//  - attn_partial software-pipelined: QK(it+1) issued before the single
//    lgkmcnt fence; double-buffered P tile; exp2 with scale folded into Q.
//  - proj_kv: fused K+V NT-GEMM (bank read once, shared A-frags), both
//    outputs staged via LDS -> coalesced 16B stores (kills vT 2B scatter).
// Shapes: B=32 S=64 D=512 M=8192 H=8 hd=64.
// ---------------------------------------------------------------------------

#define Dm  512
#define Mb  8192
#define BSr 2048
#define PLP 36   // P tile LDS row stride (u16): conflict-free b128 reads

// 0.125 (1/sqrt(hd)) * log2(e): QK^T then exp2 == softmax-exp of s/8
#define QSCALE 0.18033688011112042f

typedef float f32x4 __attribute__((ext_vector_type(4)));
typedef short bf16x8 __attribute__((ext_vector_type(8)));
typedef unsigned short u16x4 __attribute__((ext_vector_type(4)));
typedef unsigned short u16x8 __attribute__((ext_vector_type(8)));

#define MFMA(a, b, c) __builtin_amdgcn_mfma_f32_16x16x32_bf16((a), (b), (c), 0, 0, 0)

#if __has_builtin(__builtin_amdgcn_exp2f)
#define EXP2F(x) __builtin_amdgcn_exp2f(x)
#else
#define EXP2F(x) __expf((x)*0.6931471805599453f)
#endif

__device__ __forceinline__ unsigned short f32_bf16(float f) {
  unsigned u = __builtin_bit_cast(unsigned, f);
  u += 0x7FFFu + ((u >> 16) & 1u);   // RNE
  return (unsigned short)(u >> 16);
}
__device__ __forceinline__ unsigned short f32_bf16_trunc(float f) {
  return (unsigned short)(__builtin_bit_cast(unsigned, f) >> 16);
}
__device__ __forceinline__ float bf16_f32(unsigned short h) {
  unsigned u = ((unsigned)h) << 16;
  return __builtin_bit_cast(float, u);
}

// ---------------------------------------------------------------------------
// Merged fp32 -> bf16 canonicalization of all 6 tensors (4 elems/thread).
// ---------------------------------------------------------------------------
__global__ __launch_bounds__(256) void convert_all(
    const float* __restrict__ q, const float* __restrict__ bank,
    const float* __restrict__ Win, const float* __restrict__ bin,
    const float* __restrict__ Wout, const float* __restrict__ bout,
    unsigned short* __restrict__ q_c, unsigned short* __restrict__ bank_c,
    unsigned short* __restrict__ Win_c, unsigned short* __restrict__ bin_c,
    unsigned short* __restrict__ Wout_c, unsigned short* __restrict__ bout_c) {
  const int e = (blockIdx.x * 256 + threadIdx.x) * 4;
  const float* src; unsigned short* dst; int off;
  if (e < 1048576)      { src = q;    dst = q_c;    off = e; }
  else if (e < 5242880) { src = bank; dst = bank_c; off = e - 1048576; }
  else if (e < 6029312) { src = Win;  dst = Win_c;  off = e - 5242880; }
  else if (e < 6030848) { src = bin;  dst = bin_c;  off = e - 6029312; }
  else if (e < 6292992) { src = Wout; dst = Wout_c; off = e - 6030848; }
  else                  { src = bout; dst = bout_c; off = e - 6292992; }
  f32x4 v = *(const f32x4*)(src + off);
  u16x4 o;
#pragma unroll
  for (int j = 0; j < 4; ++j) o[j] = f32_bf16(v[j]);
  *(u16x4*)(dst + off) = o;
}

// ---------------------------------------------------------------------------
// Q projection: q_s[bh][s][d] = (query[m,:] @ Wq[n,:] + bq[n]) * QSCALE,
// m = b*64+s, n = h*64+d. Grid (8, 16), block 256.
// ---------------------------------------------------------------------------
__global__ __launch_bounds__(256) void proj_q(
    const unsigned short* __restrict__ A,
    const unsigned short* __restrict__ W,
    const unsigned short* __restrict__ bias,
    unsigned short* __restrict__ out) {
  const int lane = threadIdx.x & 63;
  const int wv   = threadIdx.x >> 6;
  const int l15  = lane & 15;
  const int qd   = lane >> 4;
  const int mbase = blockIdx.y * 128 + wv * 32;
  const int nbase = blockIdx.x * 64;

  const f32x4 z4 = {0.f, 0.f, 0.f, 0.f};
  f32x4 acc[2][4];
#pragma unroll
  for (int ti = 0; ti < 2; ++ti)
#pragma unroll
    for (int j = 0; j < 4; ++j) acc[ti][j] = z4;

  const unsigned short* a0p = A + (mbase + l15) * Dm + qd * 8;
  const unsigned short* a1p = a0p + 16 * Dm;
  const unsigned short* wp  = W + (nbase + l15) * Dm + qd * 8;

#pragma unroll 4
  for (int k0 = 0; k0 < Dm; k0 += 32) {
    bf16x8 a0 = *(const bf16x8*)(a0p + k0);
    bf16x8 a1 = *(const bf16x8*)(a1p + k0);
#pragma unroll
    for (int j = 0; j < 4; ++j) {
      bf16x8 b = *(const bf16x8*)(wp + j * 16 * Dm + k0);
      acc[0][j] = MFMA(a0, b, acc[0][j]);
      acc[1][j] = MFMA(a1, b, acc[1][j]);
    }
  }

#pragma unroll
  for (int ti = 0; ti < 2; ++ti) {
#pragma unroll
    for (int j = 0; j < 4; ++j) {
      const int n = nbase + j * 16 + l15;
      const float bf = bf16_f32(bias[n]);
#pragma unroll
      for (int r = 0; r < 4; ++r) {
        const int m = mbase + ti * 16 + qd * 4 + r;
        const unsigned idx = ((unsigned)(m >> 6) * 8u + (unsigned)(n >> 6)) * 4096u +
                             (unsigned)(m & 63) * 64u + (unsigned)(n & 63);
        out[idx] = f32_bf16((acc[ti][j][r] + bf) * QSCALE);
      }
    }
  }
}

// ---------------------------------------------------------------------------
// Fused K+V projection. Grid (64 m-tiles, 8 heads), block 256.
// Reads bank_c once; A-frags shared by K and V MFMAs. Outputs staged in LDS,
// stored as coalesced u16x8: k_s[h][m][d], vT_s[h*64+d][m].
// ---------------------------------------------------------------------------
__global__ __launch_bounds__(256) void proj_kv(
    const unsigned short* __restrict__ bank_c,
    const unsigned short* __restrict__ Win_c,
    const unsigned short* __restrict__ bin_c,
    unsigned short* __restrict__ k_s,
    unsigned short* __restrict__ vT_s) {
  __shared__ __align__(16) unsigned short Kst[128 * 72];   // 18.4 KB
  __shared__ __align__(16) unsigned short Vst[64 * 136];   // 17.4 KB
  const int lane = threadIdx.x & 63;
  const int wv   = threadIdx.x >> 6;
  const int l15  = lane & 15;
  const int qd   = lane >> 4;
  const int h    = blockIdx.y;
  const int mbase = blockIdx.x * 128;

  const f32x4 z4 = {0.f, 0.f, 0.f, 0.f};
  f32x4 kacc[2][4], vacc[2][4];
#pragma unroll
  for (int ti = 0; ti < 2; ++ti)
#pragma unroll
    for (int j = 0; j < 4; ++j) { kacc[ti][j] = z4; vacc[ti][j] = z4; }

  const unsigned short* a0p = bank_c + (mbase + wv * 32 + l15) * Dm + qd * 8;
  const unsigned short* a1p = a0p + 16 * Dm;
  const unsigned short* wkp = Win_c + (Dm + h * 64 + l15) * Dm + qd * 8;
  const unsigned short* wvp = Win_c + (2 * Dm + h * 64 + l15) * Dm + qd * 8;

#pragma unroll 2
  for (int k0 = 0; k0 < Dm; k0 += 32) {
    bf16x8 a0 = *(const bf16x8*)(a0p + k0);
    bf16x8 a1 = *(const bf16x8*)(a1p + k0);
#pragma unroll
    for (int j = 0; j < 4; ++j) {
      bf16x8 wk  = *(const bf16x8*)(wkp + j * 16 * Dm + k0);
      bf16x8 wvv = *(const bf16x8*)(wvp + j * 16 * Dm + k0);
      kacc[0][j] = MFMA(a0, wk, kacc[0][j]);
      kacc[1][j] = MFMA(a1, wk, kacc[1][j]);
      vacc[0][j] = MFMA(a0, wvv, vacc[0][j]);
      vacc[1][j] = MFMA(a1, wvv, vacc[1][j]);
    }
  }

#pragma unroll
  for (int ti = 0; ti < 2; ++ti) {
#pragma unroll
    for (int j = 0; j < 4; ++j) {
      const int d = j * 16 + l15;
      const float bk = bf16_f32(bin_c[Dm + h * 64 + d]);
      const float bv = bf16_f32(bin_c[2 * Dm + h * 64 + d]);
#pragma unroll
      for (int r = 0; r < 4; ++r) {
        const int m = wv * 32 + ti * 16 + qd * 4 + r;
        Kst[m * 72 + d]  = f32_bf16(kacc[ti][j][r] + bk);
        Vst[d * 136 + m] = f32_bf16(vacc[ti][j][r] + bv);
      }
    }
  }
  __syncthreads();

  // K out: 32 rows/pass, 8 lanes x 16B per row (128 B contiguous)
#pragma unroll
  for (int p = 0; p < 4; ++p) {
    const int m = p * 32 + (threadIdx.x >> 3);
    const int d = (threadIdx.x & 7) * 8;
    *(u16x8*)(k_s + h * (Mb * 64) + (mbase + m) * 64 + d) =
        *(const u16x8*)(Kst + m * 72 + d);
  }
  // V out: 16 rows/pass, 16 lanes x 16B per row (256 B contiguous)
#pragma unroll
  for (int p = 0; p < 4; ++p) {
    const int d = p * 16 + (threadIdx.x >> 4);
    const int m = (threadIdx.x & 15) * 8;
    *(u16x8*)(vT_s + (h * 64 + d) * Mb + mbase + m) =
        *(const u16x8*)(Vst + d * 136 + m);
  }
}

// ---------------------------------------------------------------------------
// Split-M attention partial, software-pipelined. Block = (bh, part); 4 waves
// own interleaved 32-key tiles. Steady-state iteration:
//   QK(it+1) -> fence (drains P writes issued BEFORE QK -> cheap) ->
//   read P(it), PV(it) -> exp2 + write P(it+1) into the other buffer.
// One lgkmcnt fence per iteration; bV loads overlap the exp/write block.
// ---------------------------------------------------------------------------
__device__ __forceinline__ void qk_tile(
    const unsigned short* __restrict__ kp, int m0, const bf16x8 aQ[4][2],
    int l15, int qd, f32x4 sfr[4][2]) {
  const f32x4 z4 = {0.f, 0.f, 0.f, 0.f};
#pragma unroll
  for (int ti = 0; ti < 4; ++ti)
#pragma unroll
    for (int tj = 0; tj < 2; ++tj) sfr[ti][tj] = z4;
#pragma unroll
  for (int tj = 0; tj < 2; ++tj) {
#pragma unroll
    for (int ks = 0; ks < 2; ++ks) {
      bf16x8 bK = *(const bf16x8*)(kp + (m0 + tj * 16 + l15) * 64 + ks * 32 + qd * 8);
#pragma unroll
      for (int ti = 0; ti < 4; ++ti) sfr[ti][tj] = MFMA(aQ[ti][ks], bK, sfr[ti][tj]);
    }
  }
}

__device__ __forceinline__ void exp_write(
    const f32x4 sfr[4][2], unsigned short* __restrict__ buf,
    int l15, int qd, float lsum[4][4]) {
#pragma unroll
  for (int ti = 0; ti < 4; ++ti) {
#pragma unroll
    for (int tj = 0; tj < 2; ++tj) {
#pragma unroll
      for (int r = 0; r < 4; ++r) {
        float e = EXP2F(sfr[ti][tj][r]);   // logits pre-scaled by 1/8*log2e
        lsum[ti][r] += e;
        buf[(ti * 16 + qd * 4 + r) * PLP + tj * 16 + l15] = f32_bf16_trunc(e);
      }
    }
  }
}

__device__ __forceinline__ void pv_tile(
    const unsigned short* __restrict__ vp, int m0,
    const unsigned short* __restrict__ buf, int l15, int qd, f32x4 oacc[4][4]) {
  bf16x8 aP[4];
#pragma unroll
  for (int ti = 0; ti < 4; ++ti)
    aP[ti] = *(const bf16x8*)(buf + (ti * 16 + l15) * PLP + qd * 8);
#pragma unroll
  for (int dt = 0; dt < 4; ++dt) {
    bf16x8 bV = *(const bf16x8*)(vp + (dt * 16 + l15) * Mb + m0 + qd * 8);
#pragma unroll
    for (int ti = 0; ti < 4; ++ti) oacc[ti][dt] = MFMA(aP[ti], bV, oacc[ti][dt]);
  }
}

__global__ __launch_bounds__(256) void attn_partial(
    const unsigned short* __restrict__ q_s,   // [bh][s][d], pre-scaled
    const unsigned short* __restrict__ k_s,   // [h][m][d]
    const unsigned short* __restrict__ vT_s,  // [h][d][m]
    unsigned short* __restrict__ O_part,      // [bh][part][s][d] bf16
    float* __restrict__ l_part) {             // [bh][part][s]
  __shared__ __align__(16) unsigned short Plds[4][2][64 * PLP];  // 36.9 KB
  __shared__ float lred[4][64];
  float* red = (float*)&Plds[0][0][0];  // epilogue alias (16 KB needed)

  const int lane = threadIdx.x & 63;
  const int wv   = threadIdx.x >> 6;
  const int l15  = lane & 15;
  const int qd   = lane >> 4;
  const int bh   = blockIdx.x >> 2;
  const int part = blockIdx.x & 3;
  const int h    = bh & 7;

  const unsigned short* qp = q_s + bh * 4096;
  const unsigned short* kp = k_s + h * (Mb * 64);
  const unsigned short* vp = vT_s + h * (Mb * 64);

  bf16x8 aQ[4][2];
#pragma unroll
  for (int ti = 0; ti < 4; ++ti)
#pragma unroll
    for (int ks = 0; ks < 2; ++ks)
      aQ[ti][ks] = *(const bf16x8*)(qp + (ti * 16 + l15) * 64 + ks * 32 + qd * 8);

  const f32x4 z4 = {0.f, 0.f, 0.f, 0.f};
  f32x4 oacc[4][4];
  float lsum[4][4];
#pragma unroll
  for (int ti = 0; ti < 4; ++ti)
#pragma unroll
    for (int j = 0; j < 4; ++j) { oacc[ti][j] = z4; lsum[ti][j] = 0.f; }

  const int mwv = part * 2048 + wv * 32;   // tile it -> m0 = mwv + it*128
  f32x4 sfr[4][2];

  // prologue: tile 0 scores -> buffer 0
  qk_tile(kp, mwv, aQ, l15, qd, sfr);
  exp_write(sfr, Plds[wv][0], l15, qd, lsum);

  for (int it = 0; it < 15; ++it) {
    qk_tile(kp, mwv + (it + 1) * 128, aQ, l15, qd, sfr);
    // drains P(it) writes -- issued before the QK above, so mostly retired
    __asm__ volatile("s_waitcnt lgkmcnt(0)" ::: "memory");
    pv_tile(vp, mwv + it * 128, Plds[wv][it & 1], l15, qd, oacc);
    exp_write(sfr, Plds[wv][(it + 1) & 1], l15, qd, lsum);
  }
  __asm__ volatile("s_waitcnt lgkmcnt(0)" ::: "memory");
  pv_tile(vp, mwv + 15 * 128, Plds[wv][1], l15, qd, oacc);

  // --- l: reduce across 16 key-lanes, then across waves ---
#pragma unroll
  for (int ti = 0; ti < 4; ++ti) {
#pragma unroll
    for (int r = 0; r < 4; ++r) {
      float v = lsum[ti][r];
      v += __shfl_xor(v, 1);
      v += __shfl_xor(v, 2);
      v += __shfl_xor(v, 4);
      v += __shfl_xor(v, 8);
      if (l15 == 0) lred[wv][ti * 16 + qd * 4 + r] = v;
    }
  }
  __syncthreads();
  if (threadIdx.x < 64)
    l_part[(bh * 4 + part) * 64 + threadIdx.x] =
        lred[0][threadIdx.x] + lred[1][threadIdx.x] +
        lred[2][threadIdx.x] + lred[3][threadIdx.x];

  // --- O: reduce across waves in 4 chunks (red aliases Plds), store bf16 ---
  unsigned short* Ob = O_part + (bh * 4 + part) * 4096;
  for (int ti = 0; ti < 4; ++ti) {
    __syncthreads();
#pragma unroll
    for (int dt = 0; dt < 4; ++dt)
#pragma unroll
      for (int r = 0; r < 4; ++r)
        red[wv * 1024 + dt * 256 + r * 64 + lane] = oacc[ti][dt][r];
    __syncthreads();
#pragma unroll
    for (int j = 0; j < 4; ++j) {
      const int idx = j * 256 + threadIdx.x;
      const float s = red[idx] + red[1024 + idx] + red[2048 + idx] + red[3072 + idx];
      const int ln = idx & 63;
      const int r  = (idx >> 6) & 3;
      const int dt = idx >> 8;
      const int srow = ti * 16 + (ln >> 4) * 4 + r;
      const int dcol = dt * 16 + (ln & 15);
      Ob[srow * 64 + dcol] = f32_bf16(s);
    }
  }
}

// ---------------------------------------------------------------------------
// Combine partials, normalize, permute to (b*64+s, h*64+d) bf16.
// ---------------------------------------------------------------------------
__global__ __launch_bounds__(256) void attn_combine(
    const unsigned short* __restrict__ O_part, const float* __restrict__ l_part,
    unsigned short* __restrict__ a_stage) {
  const int e  = (blockIdx.x * 256 + threadIdx.x) * 4;  // < 1048576
  const int bh = e >> 12;
  const int rem = e & 4095;
  const int s  = rem >> 6;
  const int d  = rem & 63;
  float acc[4] = {0.f, 0.f, 0.f, 0.f};
  float l = 0.f;
#pragma unroll
  for (int p = 0; p < 4; ++p) {
    u16x4 v = *(const u16x4*)(O_part + (bh * 4 + p) * 4096 + rem);
#pragma unroll
    for (int j = 0; j < 4; ++j) acc[j] += bf16_f32(v[j]);
    l += l_part[(bh * 4 + p) * 64 + s];
  }
  const int b = bh >> 3, h = bh & 7;
  u16x4 o;
#pragma unroll
  for (int j = 0; j < 4; ++j) o[j] = f32_bf16(acc[j] / l);
  *(u16x4*)(a_stage + (b * 64 + s) * 512 + h * 64 + d) = o;
}

// ---------------------------------------------------------------------------
// retrieved[m,n] = a_stage[m,:] @ Wout[n,:] + bout[n]  -> fp32 d_out.
// ---------------------------------------------------------------------------
__global__ __launch_bounds__(256) void out_proj(
    const unsigned short* __restrict__ A,
    const unsigned short* __restrict__ W,
    const unsigned short* __restrict__ bias,
    float* __restrict__ out) {
  const int lane = threadIdx.x & 63;
  const int wv   = threadIdx.x >> 6;
  const int l15  = lane & 15;
  const int qd   = lane >> 4;
  const int mbase = blockIdx.y * 128 + wv * 32;
  const int nbase = blockIdx.x * 64;

  const f32x4 z4 = {0.f, 0.f, 0.f, 0.f};
  f32x4 acc[2][4];
#pragma unroll
  for (int ti = 0; ti < 2; ++ti)
#pragma unroll
    for (int j = 0; j < 4; ++j) acc[ti][j] = z4;

  const unsigned short* a0p = A + (mbase + l15) * Dm + qd * 8;
  const unsigned short* a1p = a0p + 16 * Dm;
  const unsigned short* wp  = W + (nbase + l15) * Dm + qd * 8;

#pragma unroll 4
  for (int k0 = 0; k0 < Dm; k0 += 32) {
    bf16x8 a0 = *(const bf16x8*)(a0p + k0);
    bf16x8 a1 = *(const bf16x8*)(a1p + k0);
#pragma unroll
    for (int j = 0; j < 4; ++j) {
      bf16x8 bfr = *(const bf16x8*)(wp + j * 16 * Dm + k0);
      acc[0][j] = MFMA(a0, bfr, acc[0][j]);
      acc[1][j] = MFMA(a1, bfr, acc[1][j]);
    }
  }

#pragma unroll
  for (int ti = 0; ti < 2; ++ti) {
#pragma unroll
    for (int j = 0; j < 4; ++j) {
      const int n = nbase + j * 16 + l15;
      const float bf = bf16_f32(bias[n]);
#pragma unroll
      for (int r = 0; r < 4; ++r) {
        const int m = mbase + ti * 16 + qd * 4 + r;
        out[m * Dm + n] = acc[ti][j][r] + bf;
      }
    }
  }
}

// ---------------------------------------------------------------------------
// new_bank (fp32): row r <- memory[(r-ptr) mod 8192] if offset < 2048 else
// bank[r]. 16 B/thread. Overwrites the K/V scratch staged in this region.
// ---------------------------------------------------------------------------
__global__ __launch_bounds__(256) void bank_update(
    const float* __restrict__ memory, const float* __restrict__ bank,
    const int* __restrict__ ptrp, float* __restrict__ out_bank) {
  const int t  = blockIdx.x * 256 + threadIdx.x;  // < 1,048,576
  const int r  = t >> 7;
  const int c4 = (t & 127) * 4;
  const int ptr = ptrp[0];
  const unsigned off = (unsigned)(r - ptr + Mb) & (Mb - 1);
  const float* src = (off < (unsigned)BSr) ? memory + off * Dm + c4
                                           : bank + r * Dm + c4;
  *(f32x4*)(out_bank + r * Dm + c4) = *(const f32x4*)src;
}

// ---------------------------------------------------------------------------
extern "C" void kernel_launch(void* const* d_in, const int* in_sizes, int n_in,
                              void* d_out, int out_size, void* d_ws, size_t ws_size,
                              hipStream_t stream) {
  const float* query = (const float*)d_in[0];
  const float* memry = (const float*)d_in[1];
  const float* bank  = (const float*)d_in[2];
  const float* Win   = (const float*)d_in[3];
  const float* bin   = (const float*)d_in[4];
  const float* Wout  = (const float*)d_in[5];
  const float* bout  = (const float*)d_in[6];
  const int*   ptrp  = (const int*)d_in[7];
  float* outf = (float*)d_out;

  // ws layout (14.3 MB; 15.8 MB proven in round 5). Lifetime-disjoint aliases:
  // a_stage reuses q_c; O_part reuses bank_c.
  char* ws = (char*)d_ws;
  unsigned short* q_c     = (unsigned short*)(ws);                 //  0 ..  2 MB
  unsigned short* a_stage = (unsigned short*)(ws);                 //  (alias)
  unsigned short* bank_c  = (unsigned short*)(ws + (2u << 20));    //  2 .. 10 MB
  unsigned short* O_part  = (unsigned short*)(ws + (2u << 20));    //  (alias)
  unsigned short* Win_c   = (unsigned short*)(ws + (10u << 20));   // 10 .. 11.5 MB
  unsigned short* Wout_c  = (unsigned short*)(ws + 12058624u);     // 11.5 .. 12 MB
  unsigned short* q_s     = (unsigned short*)(ws + (12u << 20));   // 12 .. 14 MB
  float*          l_part  = (float*)(ws + (14u << 20));            // 14 .. 14.25 MB
  unsigned short* bin_c   = (unsigned short*)(ws + 14942208u);
  unsigned short* bout_c  = (unsigned short*)(ws + 14945280u);

  // K/V scratch lives in d_out's 16 MB bank region; bank_update rewrites it.
  unsigned short* kv = (unsigned short*)(outf + 1048576);
  unsigned short* k_s  = kv;             // 8 MB: [h][m][d]
  unsigned short* vT_s = kv + 4194304;   // 8 MB: [h][d][m]

  convert_all<<<6146, 256, 0, stream>>>(query, bank, Win, bin, Wout, bout,
                                        q_c, bank_c, Win_c, bin_c, Wout_c, bout_c);

  proj_q<<<dim3(8, 16), 256, 0, stream>>>(q_c, Win_c, bin_c, q_s);
  proj_kv<<<dim3(64, 8), 256, 0, stream>>>(bank_c, Win_c, bin_c, k_s, vT_s);

  attn_partial<<<1024, 256, 0, stream>>>(q_s, k_s, vT_s, O_part, l_part);
  attn_combine<<<1024, 256, 0, stream>>>(O_part, l_part, a_stage);

  out_proj<<<dim3(8, 16), 256, 0, stream>>>(a_stage, Wout_c, bout_c, outf);
  bank_update<<<4096, 256, 0, stream>>>(memry, bank, ptrp, outf + 1048576);
}

// Round 8
// 230.396 us; speedup vs baseline: 7.1822x; 1.0495x over previous
//
#include <hip/hip_runtime.h>

// ---------------------------------------------------------------------------
// LongTermMemoryModule, round 8. FP32 in/out. Changes vs r7:
//  - attn_partial computes S^T = K·Q^T so the MFMA C-layout lands with s on
//    lanes and keys on regs: P rows pack into ds_write_b64 (8 writes + 8
//    b64 reads per iter vs 32 scalar b16 writes + 4 b128 reads). The LDS
//    issue unit was the round-6/7 throughput floor.
//  - 5 dispatches (was 8): proj_q+proj_kv fused; attn_combine+bank_update
//    fused.
// Shapes: B=32 S=64 D=512 M=8192 H=8 hd=64.
// ---------------------------------------------------------------------------

#define Dm  512
#define Mb  8192
#define BSr 2048
#define PLP 36   // P row stride (u16): 72 B rows -> all b64 accesses 8B-aligned

// 0.125 (1/sqrt(hd)) * log2(e): exp2 after pre-scaled QK == softmax exp
#define QSCALE 0.18033688011112042f

typedef float f32x4 __attribute__((ext_vector_type(4)));
typedef short bf16x4 __attribute__((ext_vector_type(4)));
typedef short bf16x8 __attribute__((ext_vector_type(8)));
typedef unsigned short u16x4 __attribute__((ext_vector_type(4)));
typedef unsigned short u16x8 __attribute__((ext_vector_type(8)));

#define MFMA(a, b, c) __builtin_amdgcn_mfma_f32_16x16x32_bf16((a), (b), (c), 0, 0, 0)

#if __has_builtin(__builtin_amdgcn_exp2f)
#define EXP2F(x) __builtin_amdgcn_exp2f(x)
#else
#define EXP2F(x) __expf((x)*0.6931471805599453f)
#endif

__device__ __forceinline__ unsigned short f32_bf16(float f) {
  unsigned u = __builtin_bit_cast(unsigned, f);
  u += 0x7FFFu + ((u >> 16) & 1u);   // RNE
  return (unsigned short)(u >> 16);
}
__device__ __forceinline__ float bf16_f32(unsigned short h) {
  unsigned u = ((unsigned)h) << 16;
  return __builtin_bit_cast(float, u);
}
__device__ __forceinline__ unsigned pack_bf16_trunc(float a, float b) {
  // low half <- bf16(a), high half <- bf16(b); truncation rounding
  return (__builtin_bit_cast(unsigned, a) >> 16) |
         (__builtin_bit_cast(unsigned, b) & 0xFFFF0000u);
}

// ---------------------------------------------------------------------------
// Merged fp32 -> bf16 canonicalization of all 6 tensors (4 elems/thread).
// ---------------------------------------------------------------------------
__global__ __launch_bounds__(256) void convert_all(
    const float* __restrict__ q, const float* __restrict__ bank,
    const float* __restrict__ Win, const float* __restrict__ bin,
    const float* __restrict__ Wout, const float* __restrict__ bout,
    unsigned short* __restrict__ q_c, unsigned short* __restrict__ bank_c,
    unsigned short* __restrict__ Win_c, unsigned short* __restrict__ bin_c,
    unsigned short* __restrict__ Wout_c, unsigned short* __restrict__ bout_c) {
  const int e = (blockIdx.x * 256 + threadIdx.x) * 4;
  const float* src; unsigned short* dst; int off;
  if (e < 1048576)      { src = q;    dst = q_c;    off = e; }
  else if (e < 5242880) { src = bank; dst = bank_c; off = e - 1048576; }
  else if (e < 6029312) { src = Win;  dst = Win_c;  off = e - 5242880; }
  else if (e < 6030848) { src = bin;  dst = bin_c;  off = e - 6029312; }
  else if (e < 6292992) { src = Wout; dst = Wout_c; off = e - 6030848; }
  else                  { src = bout; dst = bout_c; off = e - 6292992; }
  f32x4 v = *(const f32x4*)(src + off);
  u16x4 o;
#pragma unroll
  for (int j = 0; j < 4; ++j) o[j] = f32_bf16(v[j]);
  *(u16x4*)(dst + off) = o;
}

// ---------------------------------------------------------------------------
// Fused projections. Blocks [0,128): Q projection (q_s[bh][s][d], pre-scaled
// by QSCALE). Blocks [128,640): K+V projection (k_s[h][m][d], vT_s[h*64+d][m],
// LDS-staged coalesced stores).
// ---------------------------------------------------------------------------
__global__ __launch_bounds__(256) void proj_fused(
    const unsigned short* __restrict__ q_c,
    const unsigned short* __restrict__ bank_c,
    const unsigned short* __restrict__ Win_c,
    const unsigned short* __restrict__ bin_c,
    unsigned short* __restrict__ q_s,
    unsigned short* __restrict__ k_s,
    unsigned short* __restrict__ vT_s) {
  __shared__ __align__(16) unsigned short Kst[128 * 72];
  __shared__ __align__(16) unsigned short Vst[64 * 136];
  const int lane = threadIdx.x & 63;
  const int wv   = threadIdx.x >> 6;
  const int l15  = lane & 15;
  const int qd   = lane >> 4;
  const f32x4 z4 = {0.f, 0.f, 0.f, 0.f};

  if (blockIdx.x < 128) {
    // ---------------- Q projection ----------------
    const int mbase = (blockIdx.x >> 3) * 128 + wv * 32;
    const int nbase = (blockIdx.x & 7) * 64;
    f32x4 acc[2][4];
#pragma unroll
    for (int ti = 0; ti < 2; ++ti)
#pragma unroll
      for (int j = 0; j < 4; ++j) acc[ti][j] = z4;

    const unsigned short* a0p = q_c + (mbase + l15) * Dm + qd * 8;
    const unsigned short* a1p = a0p + 16 * Dm;
    const unsigned short* wp  = Win_c + (nbase + l15) * Dm + qd * 8;

#pragma unroll 4
    for (int k0 = 0; k0 < Dm; k0 += 32) {
      bf16x8 a0 = *(const bf16x8*)(a0p + k0);
      bf16x8 a1 = *(const bf16x8*)(a1p + k0);
#pragma unroll
      for (int j = 0; j < 4; ++j) {
        bf16x8 b = *(const bf16x8*)(wp + j * 16 * Dm + k0);
        acc[0][j] = MFMA(a0, b, acc[0][j]);
        acc[1][j] = MFMA(a1, b, acc[1][j]);
      }
    }
#pragma unroll
    for (int ti = 0; ti < 2; ++ti) {
#pragma unroll
      for (int j = 0; j < 4; ++j) {
        const int n = nbase + j * 16 + l15;
        const float bf = bf16_f32(bin_c[n]);
#pragma unroll
        for (int r = 0; r < 4; ++r) {
          const int m = mbase + ti * 16 + qd * 4 + r;
          const unsigned idx = ((unsigned)(m >> 6) * 8u + (unsigned)(n >> 6)) * 4096u +
                               (unsigned)(m & 63) * 64u + (unsigned)(n & 63);
          q_s[idx] = f32_bf16((acc[ti][j][r] + bf) * QSCALE);
        }
      }
    }
    return;
  }

  // ---------------- K+V projection ----------------
  const int idx  = blockIdx.x - 128;
  const int h     = idx >> 6;
  const int mbase = (idx & 63) * 128;

  f32x4 kacc[2][4], vacc[2][4];
#pragma unroll
  for (int ti = 0; ti < 2; ++ti)
#pragma unroll
    for (int j = 0; j < 4; ++j) { kacc[ti][j] = z4; vacc[ti][j] = z4; }

  const unsigned short* a0p = bank_c + (mbase + wv * 32 + l15) * Dm + qd * 8;
  const unsigned short* a1p = a0p + 16 * Dm;
  const unsigned short* wkp = Win_c + (Dm + h * 64 + l15) * Dm + qd * 8;
  const unsigned short* wvp = Win_c + (2 * Dm + h * 64 + l15) * Dm + qd * 8;

#pragma unroll 2
  for (int k0 = 0; k0 < Dm; k0 += 32) {
    bf16x8 a0 = *(const bf16x8*)(a0p + k0);
    bf16x8 a1 = *(const bf16x8*)(a1p + k0);
#pragma unroll
    for (int j = 0; j < 4; ++j) {
      bf16x8 wk  = *(const bf16x8*)(wkp + j * 16 * Dm + k0);
      bf16x8 wvv = *(const bf16x8*)(wvp + j * 16 * Dm + k0);
      kacc[0][j] = MFMA(a0, wk, kacc[0][j]);
      kacc[1][j] = MFMA(a1, wk, kacc[1][j]);
      vacc[0][j] = MFMA(a0, wvv, vacc[0][j]);
      vacc[1][j] = MFMA(a1, wvv, vacc[1][j]);
    }
  }

#pragma unroll
  for (int ti = 0; ti < 2; ++ti) {
#pragma unroll
    for (int j = 0; j < 4; ++j) {
      const int d = j * 16 + l15;
      const float bk = bf16_f32(bin_c[Dm + h * 64 + d]);
      const float bv = bf16_f32(bin_c[2 * Dm + h * 64 + d]);
#pragma unroll
      for (int r = 0; r < 4; ++r) {
        const int m = wv * 32 + ti * 16 + qd * 4 + r;
        Kst[m * 72 + d]  = f32_bf16(kacc[ti][j][r] + bk);
        Vst[d * 136 + m] = f32_bf16(vacc[ti][j][r] + bv);
      }
    }
  }
  __syncthreads();

#pragma unroll
  for (int p = 0; p < 4; ++p) {
    const int m = p * 32 + (threadIdx.x >> 3);
    const int d = (threadIdx.x & 7) * 8;
    *(u16x8*)(k_s + h * (Mb * 64) + (mbase + m) * 64 + d) =
        *(const u16x8*)(Kst + m * 72 + d);
  }
#pragma unroll
  for (int p = 0; p < 4; ++p) {
    const int d = p * 16 + (threadIdx.x >> 4);
    const int m = (threadIdx.x & 15) * 8;
    *(u16x8*)(vT_s + (h * 64 + d) * Mb + mbase + m) =
        *(const u16x8*)(Vst + d * 136 + m);
  }
}

// ---------------------------------------------------------------------------
// Attention partial, S^T formulation. Block = (bh, part); wave wv owns key
// tiles m0 = part*2048 + wv*32 + it*128, it=0..15 (32 keys each).
//  QK: S^T = K·Q^T -> C layout col=l15=s, row=quad*4+r=key (r contiguous in
//  row-major P[s][key]) -> exp2 -> pack 4 bf16 -> ONE ds_write_b64 per tile.
//  PV: A-frag = two ds_read_b64 per s-tile; B = vT global. 16 DS ops/iter.
// ---------------------------------------------------------------------------
__device__ __forceinline__ void qk_tile(
    const unsigned short* __restrict__ kp, int m0, const bf16x8 bQ[4][2],
    int l15, int qd, f32x4 sfr[2][4]) {
  const f32x4 z4 = {0.f, 0.f, 0.f, 0.f};
#pragma unroll
  for (int kt = 0; kt < 2; ++kt)
#pragma unroll
    for (int sj = 0; sj < 4; ++sj) sfr[kt][sj] = z4;
#pragma unroll
  for (int kt = 0; kt < 2; ++kt) {
#pragma unroll
    for (int ks = 0; ks < 2; ++ks) {
      bf16x8 aK = *(const bf16x8*)(kp + (m0 + kt * 16 + l15) * 64 + ks * 32 + qd * 8);
#pragma unroll
      for (int sj = 0; sj < 4; ++sj) sfr[kt][sj] = MFMA(aK, bQ[sj][ks], sfr[kt][sj]);
    }
  }
}

__device__ __forceinline__ void exp_write(
    const f32x4 sfr[2][4], unsigned short* __restrict__ buf,
    int l15, int qd, float lsum[4]) {
#pragma unroll
  for (int kt = 0; kt < 2; ++kt) {
#pragma unroll
    for (int sj = 0; sj < 4; ++sj) {
      float e0 = EXP2F(sfr[kt][sj][0]);
      float e1 = EXP2F(sfr[kt][sj][1]);
      float e2 = EXP2F(sfr[kt][sj][2]);
      float e3 = EXP2F(sfr[kt][sj][3]);
      lsum[sj] += (e0 + e1) + (e2 + e3);
      uint2 dw;
      dw.x = pack_bf16_trunc(e0, e1);
      dw.y = pack_bf16_trunc(e2, e3);
      *(uint2*)(buf + (sj * 16 + l15) * PLP + kt * 16 + qd * 4) = dw;
    }
  }
}

__device__ __forceinline__ void pv_tile(
    const unsigned short* __restrict__ vp, int m0,
    const unsigned short* __restrict__ buf, int l15, int qd, f32x4 oacc[4][4]) {
  bf16x8 aP[4];
#pragma unroll
  for (int ti = 0; ti < 4; ++ti) {
    const unsigned short* pp = buf + (ti * 16 + l15) * PLP + qd * 8;
    bf16x4 lo = *(const bf16x4*)(pp);
    bf16x4 hi = *(const bf16x4*)(pp + 4);
    aP[ti] = __builtin_shufflevector(lo, hi, 0, 1, 2, 3, 4, 5, 6, 7);
  }
#pragma unroll
  for (int dt = 0; dt < 4; ++dt) {
    bf16x8 bV = *(const bf16x8*)(vp + (dt * 16 + l15) * Mb + m0 + qd * 8);
#pragma unroll
    for (int ti = 0; ti < 4; ++ti) oacc[ti][dt] = MFMA(aP[ti], bV, oacc[ti][dt]);
  }
}

__global__ __launch_bounds__(256) void attn_partial(
    const unsigned short* __restrict__ q_s,   // [bh][s][d], pre-scaled
    const unsigned short* __restrict__ k_s,   // [h][m][d]
    const unsigned short* __restrict__ vT_s,  // [h][d][m]
    unsigned short* __restrict__ O_part,      // [bh][part][s][d] bf16
    float* __restrict__ l_part) {             // [bh][part][s]
  __shared__ __align__(16) unsigned short Plds[4][2][64 * PLP];  // 36 KB
  __shared__ float lred[4][64];
  float* red = (float*)&Plds[0][0][0];  // epilogue alias (16 KB needed)

  const int lane = threadIdx.x & 63;
  const int wv   = threadIdx.x >> 6;
  const int l15  = lane & 15;
  const int qd   = lane >> 4;
  const int bh   = blockIdx.x >> 2;
  const int part = blockIdx.x & 3;
  const int h    = bh & 7;

  const unsigned short* qp = q_s + bh * 4096;
  const unsigned short* kp = k_s + h * (Mb * 64);
  const unsigned short* vp = vT_s + h * (Mb * 64);

  // Q as B-operand: B[k=d][n=s], n = l15 -> row s = sj*16+l15 of q_s
  bf16x8 bQ[4][2];
#pragma unroll
  for (int sj = 0; sj < 4; ++sj)
#pragma unroll
    for (int ks = 0; ks < 2; ++ks)
      bQ[sj][ks] = *(const bf16x8*)(qp + (sj * 16 + l15) * 64 + ks * 32 + qd * 8);

  const f32x4 z4 = {0.f, 0.f, 0.f, 0.f};
  f32x4 oacc[4][4];
  float lsum[4] = {0.f, 0.f, 0.f, 0.f};
#pragma unroll
  for (int ti = 0; ti < 4; ++ti)
#pragma unroll
    for (int j = 0; j < 4; ++j) oacc[ti][j] = z4;

  const int mwv = part * 2048 + wv * 32;
  f32x4 sfr[2][4];

  qk_tile(kp, mwv, bQ, l15, qd, sfr);
  exp_write(sfr, Plds[wv][0], l15, qd, lsum);

  for (int it = 0; it < 15; ++it) {
    qk_tile(kp, mwv + (it + 1) * 128, bQ, l15, qd, sfr);
    __asm__ volatile("s_waitcnt lgkmcnt(0)" ::: "memory");  // P(it) writes drained
    pv_tile(vp, mwv + it * 128, Plds[wv][it & 1], l15, qd, oacc);
    exp_write(sfr, Plds[wv][(it + 1) & 1], l15, qd, lsum);
  }
  __asm__ volatile("s_waitcnt lgkmcnt(0)" ::: "memory");
  pv_tile(vp, mwv + 15 * 128, Plds[wv][1], l15, qd, oacc);

  // --- l: lane holds partial for s = sj*16+l15 over its keys; reduce quads ---
#pragma unroll
  for (int sj = 0; sj < 4; ++sj) {
    float v = lsum[sj];
    v += __shfl_xor(v, 16);
    v += __shfl_xor(v, 32);
    if (qd == 0) lred[wv][sj * 16 + l15] = v;
  }
  __syncthreads();
  if (threadIdx.x < 64)
    l_part[(bh * 4 + part) * 64 + threadIdx.x] =
        lred[0][threadIdx.x] + lred[1][threadIdx.x] +
        lred[2][threadIdx.x] + lred[3][threadIdx.x];

  // --- O: reduce across waves in 4 chunks (red aliases Plds), store bf16 ---
  unsigned short* Ob = O_part + (bh * 4 + part) * 4096;
  for (int ti = 0; ti < 4; ++ti) {
    __syncthreads();
#pragma unroll
    for (int dt = 0; dt < 4; ++dt)
#pragma unroll
      for (int r = 0; r < 4; ++r)
        red[wv * 1024 + dt * 256 + r * 64 + lane] = oacc[ti][dt][r];
    __syncthreads();
#pragma unroll
    for (int j = 0; j < 4; ++j) {
      const int idx = j * 256 + threadIdx.x;
      const float s = red[idx] + red[1024 + idx] + red[2048 + idx] + red[3072 + idx];
      const int ln = idx & 63;
      const int r  = (idx >> 6) & 3;
      const int dt = idx >> 8;
      const int srow = ti * 16 + (ln >> 4) * 4 + r;
      const int dcol = dt * 16 + (ln & 15);
      Ob[srow * 64 + dcol] = f32_bf16(s);
    }
  }
}

// ---------------------------------------------------------------------------
// Fused: blocks [0,1024) combine attention partials -> a_stage bf16;
// blocks [1024,5120) write new_bank fp32 (overwrites the K/V scratch).
// Both depend only on attn_partial; disjoint memory.
// ---------------------------------------------------------------------------
__global__ __launch_bounds__(256) void combine_bank(
    const unsigned short* __restrict__ O_part, const float* __restrict__ l_part,
    unsigned short* __restrict__ a_stage,
    const float* __restrict__ memory, const float* __restrict__ bank,
    const int* __restrict__ ptrp, float* __restrict__ out_bank) {
  if (blockIdx.x < 1024) {
    const int e  = (blockIdx.x * 256 + threadIdx.x) * 4;  // < 1048576
    const int bh = e >> 12;
    const int rem = e & 4095;
    const int s  = rem >> 6;
    const int d  = rem & 63;
    float acc[4] = {0.f, 0.f, 0.f, 0.f};
    float l = 0.f;
#pragma unroll
    for (int p = 0; p < 4; ++p) {
      u16x4 v = *(const u16x4*)(O_part + (bh * 4 + p) * 4096 + rem);
#pragma unroll
      for (int j = 0; j < 4; ++j) acc[j] += bf16_f32(v[j]);
      l += l_part[(bh * 4 + p) * 64 + s];
    }
    const int b = bh >> 3, h = bh & 7;
    u16x4 o;
#pragma unroll
    for (int j = 0; j < 4; ++j) o[j] = f32_bf16(acc[j] / l);
    *(u16x4*)(a_stage + (b * 64 + s) * 512 + h * 64 + d) = o;
  } else {
    const int t  = (blockIdx.x - 1024) * 256 + threadIdx.x;  // < 1,048,576
    const int r  = t >> 7;
    const int c4 = (t & 127) * 4;
    const int ptr = ptrp[0];
    const unsigned off = (unsigned)(r - ptr + Mb) & (Mb - 1);
    const float* src = (off < (unsigned)BSr) ? memory + off * Dm + c4
                                             : bank + r * Dm + c4;
    *(f32x4*)(out_bank + r * Dm + c4) = *(const f32x4*)src;
  }
}

// ---------------------------------------------------------------------------
// retrieved[m,n] = a_stage[m,:] @ Wout[n,:] + bout[n]  -> fp32 d_out.
// ---------------------------------------------------------------------------
__global__ __launch_bounds__(256) void out_proj(
    const unsigned short* __restrict__ A,
    const unsigned short* __restrict__ W,
    const unsigned short* __restrict__ bias,
    float* __restrict__ out) {
  const int lane = threadIdx.x & 63;
  const int wv   = threadIdx.x >> 6;
  const int l15  = lane & 15;
  const int qd   = lane >> 4;
  const int mbase = blockIdx.y * 128 + wv * 32;
  const int nbase = blockIdx.x * 64;

  const f32x4 z4 = {0.f, 0.f, 0.f, 0.f};
  f32x4 acc[2][4];
#pragma unroll
  for (int ti = 0; ti < 2; ++ti)
#pragma unroll
    for (int j = 0; j < 4; ++j) acc[ti][j] = z4;

  const unsigned short* a0p = A + (mbase + l15) * Dm + qd * 8;
  const unsigned short* a1p = a0p + 16 * Dm;
  const unsigned short* wp  = W + (nbase + l15) * Dm + qd * 8;

#pragma unroll 4
  for (int k0 = 0; k0 < Dm; k0 += 32) {
    bf16x8 a0 = *(const bf16x8*)(a0p + k0);
    bf16x8 a1 = *(const bf16x8*)(a1p + k0);
#pragma unroll
    for (int j = 0; j < 4; ++j) {
      bf16x8 bfr = *(const bf16x8*)(wp + j * 16 * Dm + k0);
      acc[0][j] = MFMA(a0, bfr, acc[0][j]);
      acc[1][j] = MFMA(a1, bfr, acc[1][j]);
    }
  }

#pragma unroll
  for (int ti = 0; ti < 2; ++ti) {
#pragma unroll
    for (int j = 0; j < 4; ++j) {
      const int n = nbase + j * 16 + l15;
      const float bf = bf16_f32(bias[n]);
#pragma unroll
      for (int r = 0; r < 4; ++r) {
        const int m = mbase + ti * 16 + qd * 4 + r;
        out[m * Dm + n] = acc[ti][j][r] + bf;
      }
    }
  }
}

// ---------------------------------------------------------------------------
extern "C" void kernel_launch(void* const* d_in, const int* in_sizes, int n_in,
                              void* d_out, int out_size, void* d_ws, size_t ws_size,
                              hipStream_t stream) {
  const float* query = (const float*)d_in[0];
  const float* memry = (const float*)d_in[1];
  const float* bank  = (const float*)d_in[2];
  const float* Win   = (const float*)d_in[3];
  const float* bin   = (const float*)d_in[4];
  const float* Wout  = (const float*)d_in[5];
  const float* bout  = (const float*)d_in[6];
  const int*   ptrp  = (const int*)d_in[7];
  float* outf = (float*)d_out;

  // ws layout (14.3 MB; 15.8 MB proven). Lifetime-disjoint aliases:
  // a_stage reuses q_c; O_part reuses bank_c.
  char* ws = (char*)d_ws;
  unsigned short* q_c     = (unsigned short*)(ws);                 //  0 ..  2 MB
  unsigned short* a_stage = (unsigned short*)(ws);                 //  (alias)
  unsigned short* bank_c  = (unsigned short*)(ws + (2u << 20));    //  2 .. 10 MB
  unsigned short* O_part  = (unsigned short*)(ws + (2u << 20));    //  (alias)
  unsigned short* Win_c   = (unsigned short*)(ws + (10u << 20));   // 10 .. 11.5 MB
  unsigned short* Wout_c  = (unsigned short*)(ws + 12058624u);     // 11.5 .. 12 MB
  unsigned short* q_s     = (unsigned short*)(ws + (12u << 20));   // 12 .. 14 MB
  float*          l_part  = (float*)(ws + (14u << 20));            // 14 .. 14.25 MB
  unsigned short* bin_c   = (unsigned short*)(ws + 14942208u);
  unsigned short* bout_c  = (unsigned short*)(ws + 14945280u);

  // K/V scratch in d_out's bank region; combine_bank rewrites it afterwards.
  unsigned short* kv = (unsigned short*)(outf + 1048576);
  unsigned short* k_s  = kv;             // 8 MB: [h][m][d]
  unsigned short* vT_s = kv + 4194304;   // 8 MB: [h][d][m]

  convert_all<<<6146, 256, 0, stream>>>(query, bank, Win, bin, Wout, bout,
                                        q_c, bank_c, Win_c, bin_c, Wout_c, bout_c);

  proj_fused<<<640, 256, 0, stream>>>(q_c, bank_c, Win_c, bin_c, q_s, k_s, vT_s);

  attn_partial<<<1024, 256, 0, stream>>>(q_s, k_s, vT_s, O_part, l_part);

  combine_bank<<<5120, 256, 0, stream>>>(O_part, l_part, a_stage,
                                         memry, bank, ptrp, outf + 1048576);

  out_proj<<<dim3(8, 16), 256, 0, stream>>>(a_stage, Wout_c, bout_c, outf);
}